// Round 4
// baseline (295.928 us; speedup 1.0000x reference)
//
#include <hip/hip_runtime.h>
#include <stdint.h>

typedef unsigned short u16;
typedef __attribute__((ext_vector_type(4))) float f32x4;
typedef __attribute__((ext_vector_type(2))) __bf16 bf16x2;
typedef __attribute__((ext_vector_type(8))) __bf16 bf16x8;
typedef __attribute__((ext_vector_type(4))) u16 u16x4;

#define AS1 __attribute__((address_space(1)))
#define AS3 __attribute__((address_space(3)))
#define GLOAD_LDS16(gp, lp) \
  __builtin_amdgcn_global_load_lds((const AS1 void*)(gp), (AS3 void*)(lp), 16, 0, 0)

__device__ __forceinline__ u16 f2bf(float f) {
  union { float f; unsigned u; } v; v.f = f;
  return (u16)((v.u + 0x7FFFu + ((v.u >> 16) & 1u)) >> 16);
}
__device__ __forceinline__ float bf2f(u16 u) {
  union { unsigned u; float f; } v; v.u = ((unsigned)u) << 16; return v.f;
}
__device__ __forceinline__ float fexp2(float x) {
#if __has_builtin(__builtin_amdgcn_exp2f)
  return __builtin_amdgcn_exp2f(x);
#else
  return exp2f(x);
#endif
}
__device__ __forceinline__ u16x4 pack4(float a, float b, float c, float d) {
#if __has_builtin(__builtin_amdgcn_cvt_pk_bf16_f32)
  union { struct { bf16x2 lo, hi; } p; u16x4 v; } u;
  u.p.lo = __builtin_amdgcn_cvt_pk_bf16_f32(a, b);
  u.p.hi = __builtin_amdgcn_cvt_pk_bf16_f32(c, d);
  return u.v;
#else
  u16x4 r; r.x = f2bf(a); r.y = f2bf(b); r.z = f2bf(c); r.w = f2bf(d); return r;
#endif
}

#define LOG2E 1.44269504f

// ---------- fp32 -> bf16 conversion ----------
// Wq scaled by log2e/8 (fold softmax 1/sqrt(64) + exp2 domain); mask scaled by log2e.
__global__ __launch_bounds__(256) void convert_all(
    const float* __restrict__ x, const float* __restrict__ y,
    const float* __restrict__ wq, const float* __restrict__ wk,
    const float* __restrict__ wv, const float* __restrict__ wo,
    const float* __restrict__ mask,
    u16* __restrict__ xb, u16* __restrict__ yb, u16* __restrict__ wqb,
    u16* __restrict__ wkb, u16* __restrict__ wvb, u16* __restrict__ wob,
    u16* __restrict__ maskb) {
  size_t i = (size_t)blockIdx.x * 256 + threadIdx.x;  // float4 index, 4M total
  const float* src; u16* dst; float scale = 1.0f; size_t off;
  if (i < (size_t)(1u << 20)) { src = x; dst = xb; off = i; }
  else if (i < (size_t)(2u << 20)) { src = y; dst = yb; off = i - (1u << 20); }
  else if (i < (size_t)(3u << 20)) {
    size_t j = i - (size_t)(2u << 20);
    unsigned w = (unsigned)(j >> 18); off = j & ((1u << 18) - 1);
    if (w == 0)      { src = wq; dst = wqb; scale = 0.125f * LOG2E; }
    else if (w == 1) { src = wk; dst = wkb; }
    else if (w == 2) { src = wv; dst = wvb; }
    else             { src = wo; dst = wob; }
  } else { src = mask; dst = maskb; scale = LOG2E; off = i - (size_t)(3u << 20); }
  f32x4 v = ((const f32x4*)src)[off];
  ((u16x4*)dst)[off] = pack4(v.x * scale, v.y * scale, v.z * scale, v.w * scale);
}

// ---------- BT-GEMM core: 128x128 tile, K=1024, BK=64, XOR-swizzled LDS ----------
__device__ __forceinline__ void gemm_core64(
    const u16* __restrict__ A, const u16* __restrict__ Bt, int tm, int tn,
    u16* As, u16* Bs, f32x4 acc[4][4], int wave, int lane) {
  constexpr int K = 1024;
  const int l15 = lane & 15, quad = lane >> 4;
  const int wr = wave >> 1, wc = wave & 1;
  const int srow = lane >> 3;
  const int scol = ((lane & 7) ^ (srow & 7)) * 8;
  const u16* Ag = A + (size_t)(tm + wave * 32 + srow) * K + scol;
  const u16* Bg = Bt + (size_t)(tn + wave * 32 + srow) * K + scol;
  const int rsw = l15 & 7;

  for (int k0 = 0; k0 < K; k0 += 64) {
    __syncthreads();
#pragma unroll
    for (int c = 0; c < 4; ++c)
      GLOAD_LDS16(Ag + (size_t)c * 8 * K + k0, &As[(wave * 4 + c) * 512]);
#pragma unroll
    for (int c = 0; c < 4; ++c)
      GLOAD_LDS16(Bg + (size_t)c * 8 * K + k0, &Bs[(wave * 4 + c) * 512]);
    __syncthreads();
#pragma unroll
    for (int kq = 0; kq < 2; ++kq) {
      bf16x8 af[4], bfr[4];
#pragma unroll
      for (int mi = 0; mi < 4; ++mi)
        af[mi] = *(const bf16x8*)&As[(wr * 64 + mi * 16 + l15) * 64 +
                                     ((kq * 4 + quad) ^ rsw) * 8];
#pragma unroll
      for (int ni = 0; ni < 4; ++ni)
        bfr[ni] = *(const bf16x8*)&Bs[(wc * 64 + ni * 16 + l15) * 64 +
                                      ((kq * 4 + quad) ^ rsw) * 8];
#pragma unroll
      for (int mi = 0; mi < 4; ++mi)
#pragma unroll
        for (int ni = 0; ni < 4; ++ni)
          acc[mi][ni] = __builtin_amdgcn_mfma_f32_16x16x32_bf16(
              af[mi], bfr[ni], acc[mi][ni], 0, 0, 0);
    }
  }
}

// ---------- fused Q/K/Vt projections ----------
__global__ __launch_bounds__(256, 3) void qkv_gemm(
    const u16* __restrict__ xb, const u16* __restrict__ yb,
    const u16* __restrict__ wqb, const u16* __restrict__ wkb,
    const u16* __restrict__ wvb,
    u16* __restrict__ Qw, u16* __restrict__ Kw, u16* __restrict__ Vtw) {
  __shared__ __align__(16) u16 As[128 * 64];
  __shared__ __align__(16) u16 Bs[128 * 64];
  const int tid = threadIdx.x, wave = tid >> 6, lane = tid & 63;
  const int l15 = lane & 15, quad = lane >> 4;
  const int wr = wave >> 1, wc = wave & 1;
  const int z = blockIdx.z;
  const u16 *A, *Bt; int tm, tn;
  if (z == 0)      { A = yb;  Bt = wqb; tm = blockIdx.y * 128; tn = blockIdx.x * 128; }
  else if (z == 1) { A = xb;  Bt = wkb; tm = blockIdx.y * 128; tn = blockIdx.x * 128; }
  else             { A = wvb; Bt = xb;  tm = blockIdx.x * 128; tn = blockIdx.y * 128; }

  f32x4 acc[4][4] = {};
  gemm_core64(A, Bt, tm, tn, As, Bs, acc, wave, lane);

#pragma unroll
  for (int mi = 0; mi < 4; ++mi) {
#pragma unroll
    for (int ni = 0; ni < 4; ++ni) {
#pragma unroll
      for (int r = 0; r < 4; ++r) {
        int gm = tm + wr * 64 + mi * 16 + quad * 4 + r;
        int gn = tn + wc * 64 + ni * 16 + l15;
        u16 val = f2bf(acc[mi][ni][r]);
        if (z == 2) {  // Vt: [B][H][64][S]
          int h = gm >> 6, dh = gm & 63, b = gn >> 11, s = gn & 2047;
          Vtw[(((size_t)(b * 16 + h) * 64 + dh) << 11) + s] = val;
        } else {       // Q/K: [B][H][S][64]
          int b = gm >> 11, s = gm & 2047, h = gn >> 6, dh = gn & 63;
          u16* dst = (z == 0) ? Qw : Kw;
          dst[(((size_t)(b * 16 + h) * 2048 + s) << 6) + dh] = val;
        }
      }
    }
  }
}

// ---------- output projection: fp32 out ----------
__global__ __launch_bounds__(256, 3) void out_gemm(
    const u16* __restrict__ Ow, const u16* __restrict__ wob,
    float* __restrict__ C) {
  __shared__ __align__(16) u16 As[128 * 64];
  __shared__ __align__(16) u16 Bs[128 * 64];
  const int tid = threadIdx.x, wave = tid >> 6, lane = tid & 63;
  const int l15 = lane & 15, quad = lane >> 4;
  const int wr = wave >> 1, wc = wave & 1;
  const int tm = blockIdx.y * 128, tn = blockIdx.x * 128;

  f32x4 acc[4][4] = {};
  gemm_core64(Ow, wob, tm, tn, As, Bs, acc, wave, lane);

#pragma unroll
  for (int mi = 0; mi < 4; ++mi)
#pragma unroll
    for (int ni = 0; ni < 4; ++ni)
#pragma unroll
      for (int r = 0; r < 4; ++r) {
        int gm = tm + wr * 64 + mi * 16 + quad * 4 + r;
        int gn = tn + wc * 64 + ni * 16 + l15;
        C[(size_t)gm * 1024 + gn] = acc[mi][ni][r];
      }
}

// ---------- flash-style attention v4: key-split + kt=64, 4 blocks/CU ----------
// grid (qt=16, h=16, z=4): z = b*2+ks; block does 128 q x 1024 keys, 16 iters.
// Unnormalized partials: Op[ks] f32 [B][S][1024], den f32 [ks][B][H][S].
__global__ __launch_bounds__(256, 4) void attn_kernel(
    const u16* __restrict__ Qw, const u16* __restrict__ Kw,
    const u16* __restrict__ Vtw, const u16* __restrict__ maskb,
    float* __restrict__ Op0, float* __restrict__ Op1, float* __restrict__ denb) {
  constexpr int S = 2048;
  constexpr int PADK = 72;
  __shared__ __align__(16) u16 Ks[64 * 64];    // [key][dh], cb c at slot c^(key&7)
  __shared__ __align__(16) u16 Vs[64 * 64];    // [dh][key], cb c at slot c^(dh&7)
  __shared__ __align__(16) u16 Ps[128 * PADK]; // [q][key] bf16
  const int tid = threadIdx.x;
  const int wave = tid >> 6, lane = tid & 63;
  const int l15 = lane & 15, quad = lane >> 4;
  const int qt = blockIdx.x, h = blockIdx.y, z = blockIdx.z;
  const int b = z >> 1, ks = z & 1;
  const size_t head = ((size_t)(b * 16 + h)) * S * 64;
  const int kbase = ks * 1024;
  const int qbase = qt * 128 + wave * 32;  // wave owns 32 q-rows

  // Q B-frags in registers: B[n=q=l15][k=quad*8+j]  (pre-scaled by log2e/8)
  bf16x8 qf[2][2];
#pragma unroll
  for (int q2 = 0; q2 < 2; ++q2)
#pragma unroll
    for (int kq = 0; kq < 2; ++kq)
      qf[q2][kq] = *(const bf16x8*)&Qw[head +
          (size_t)(qbase + q2 * 16 + l15) * 64 + kq * 32 + quad * 8];

  const __bf16 one_bf = (__bf16)1.0f;
  const bf16x8 ones = {one_bf, one_bf, one_bf, one_bf, one_bf, one_bf, one_bf, one_bf};

  f32x4 oa[2][4] = {};
  f32x4 den[2] = {};

  // staging: chunk g = wave*2+c (1KB) = 8 rows x 128B; lane: row g*8+(l>>3),
  // slot l&7 <- global colblk (l&7)^(row&7)  (row&7 == l>>3)
  const int s_r = lane >> 3;
  const int s_c = ((lane & 7) ^ s_r) * 8;
  const int rsw = l15 & 7;

  for (int kt = 0; kt < 1024; kt += 64) {
    __syncthreads();
#pragma unroll
    for (int c = 0; c < 2; ++c) {
      int g = wave * 2 + c;
      GLOAD_LDS16(&Kw[head + (size_t)(kbase + kt + g * 8 + s_r) * 64 + s_c],
                  &Ks[g * 512]);
    }
#pragma unroll
    for (int c = 0; c < 2; ++c) {
      int g = wave * 2 + c;
      int dh = g * 8 + s_r;
      GLOAD_LDS16(&Vtw[head + (size_t)dh * S + kbase + kt + s_c], &Vs[g * 512]);
    }
    // mask loads (bf16, pre-scaled log2e): 4 consecutive keys per lane
    u16x4 mq[2][4];
#pragma unroll
    for (int q2 = 0; q2 < 2; ++q2)
#pragma unroll
      for (int mk = 0; mk < 4; ++mk)
        mq[q2][mk] = *(const u16x4*)&maskb[(size_t)(qbase + q2 * 16 + l15) * S +
                                           kbase + kt + mk * 16 + quad * 4];
    __syncthreads();

    // S^T = K·Q^T : m=key (4 tiles), n=query (2 tiles); A-frag shared across q
    f32x4 sa[2][4] = {};
#pragma unroll
    for (int kq = 0; kq < 2; ++kq) {
#pragma unroll
      for (int mk = 0; mk < 4; ++mk) {
        bf16x8 ak = *(const bf16x8*)&Ks[(mk * 16 + l15) * 64 +
                                        ((kq * 4 + quad) ^ rsw) * 8];
        sa[0][mk] = __builtin_amdgcn_mfma_f32_16x16x32_bf16(ak, qf[0][kq], sa[0][mk], 0, 0, 0);
        sa[1][mk] = __builtin_amdgcn_mfma_f32_16x16x32_bf16(ak, qf[1][kq], sa[1][mk], 0, 0, 0);
      }
    }

    // P = exp2(S + mask) -> Ps (wave-exclusive rows; no barrier needed)
#pragma unroll
    for (int q2 = 0; q2 < 2; ++q2) {
#pragma unroll
      for (int mk = 0; mk < 4; ++mk) {
        float p0 = fexp2(sa[q2][mk][0] + bf2f(mq[q2][mk].x));
        float p1 = fexp2(sa[q2][mk][1] + bf2f(mq[q2][mk].y));
        float p2 = fexp2(sa[q2][mk][2] + bf2f(mq[q2][mk].z));
        float p3 = fexp2(sa[q2][mk][3] + bf2f(mq[q2][mk].w));
        *(u16x4*)&Ps[(wave * 32 + q2 * 16 + l15) * PADK + mk * 16 + quad * 4] =
            pack4(p0, p1, p2, p3);
      }
    }

    // O += P·V ; den += P·1
#pragma unroll
    for (int kq2 = 0; kq2 < 2; ++kq2) {
      bf16x8 ap0 = *(const bf16x8*)&Ps[(wave * 32 + l15) * PADK + kq2 * 32 + quad * 8];
      bf16x8 ap1 = *(const bf16x8*)&Ps[(wave * 32 + 16 + l15) * PADK + kq2 * 32 + quad * 8];
#pragma unroll
      for (int nv = 0; nv < 4; ++nv) {
        bf16x8 bv = *(const bf16x8*)&Vs[(nv * 16 + l15) * 64 +
                                        ((kq2 * 4 + quad) ^ rsw) * 8];
        oa[0][nv] = __builtin_amdgcn_mfma_f32_16x16x32_bf16(ap0, bv, oa[0][nv], 0, 0, 0);
        oa[1][nv] = __builtin_amdgcn_mfma_f32_16x16x32_bf16(ap1, bv, oa[1][nv], 0, 0, 0);
      }
      den[0] = __builtin_amdgcn_mfma_f32_16x16x32_bf16(ap0, ones, den[0], 0, 0, 0);
      den[1] = __builtin_amdgcn_mfma_f32_16x16x32_bf16(ap1, ones, den[1], 0, 0, 0);
    }
  }

  // epilogue: unnormalized partials (f32) + den
  float* Op = ks ? Op1 : Op0;
#pragma unroll
  for (int q2 = 0; q2 < 2; ++q2) {
#pragma unroll
    for (int nv = 0; nv < 4; ++nv) {
#pragma unroll
      for (int r = 0; r < 4; ++r) {
        int srow = qbase + q2 * 16 + quad * 4 + r;
        int dh = nv * 16 + l15;
        Op[((size_t)(b * S + srow) << 10) + h * 64 + dh] = oa[q2][nv][r];
      }
    }
  }
  if (l15 == 0) {
#pragma unroll
    for (int q2 = 0; q2 < 2; ++q2)
#pragma unroll
      for (int r = 0; r < 4; ++r) {
        int srow = qbase + q2 * 16 + quad * 4 + r;
        denb[((size_t)(ks * 2 + b) * 16 + h) * 2048 + srow] = den[q2][r];
      }
  }
}

// ---------- combine partials -> Ow bf16 ----------
__global__ __launch_bounds__(256) void combine(
    const float* __restrict__ Op0, const float* __restrict__ Op1,
    const float* __restrict__ denb, u16* __restrict__ Ow) {
  size_t i = (size_t)blockIdx.x * 256 + threadIdx.x;  // f32x4 idx over 1M
  size_t flat = i * 4;
  int c = (int)(flat & 1023), h = c >> 6;
  int s = (int)((flat >> 10) & 2047);
  int b = (int)(flat >> 21);
  f32x4 a = ((const f32x4*)Op0)[i];
  f32x4 d = ((const f32x4*)Op1)[i];
  float dn = denb[((size_t)b * 16 + h) * 2048 + s] +
             denb[((size_t)(2 + b) * 16 + h) * 2048 + s] + 1e-10f;
  float r = 1.0f / dn;
  ((u16x4*)Ow)[i] = pack4((a.x + d.x) * r, (a.y + d.y) * r,
                          (a.z + d.z) * r, (a.w + d.w) * r);
}

extern "C" void kernel_launch(void* const* d_in, const int* in_sizes, int n_in,
                              void* d_out, int out_size, void* d_ws, size_t ws_size,
                              hipStream_t stream) {
  const float* x    = (const float*)d_in[0];
  const float* y    = (const float*)d_in[1];
  const float* mask = (const float*)d_in[2];
  const float* Wq   = (const float*)d_in[3];
  const float* Wk   = (const float*)d_in[4];
  const float* Wv   = (const float*)d_in[5];
  const float* Wo   = (const float*)d_in[6];
  char* ws = (char*)d_ws;
  const size_t MB = (size_t)1 << 20;
  // phase-1 layout
  u16* xb  = (u16*)(ws + 0  * MB);     // dead after qkv_gemm
  u16* yb  = (u16*)(ws + 8  * MB);     // dead after qkv_gemm
  u16* wqb = (u16*)(ws + 16 * MB);     // dead after qkv_gemm
  u16* wkb = (u16*)(ws + 18 * MB);
  u16* wvb = (u16*)(ws + 20 * MB);
  u16* wob = (u16*)(ws + 22 * MB);     // needed by out_gemm
  u16* Qw  = (u16*)(ws + 24 * MB);     // [B][H][S][64] bf16, scaled log2e/8
  u16* Kw  = (u16*)(ws + 32 * MB);
  u16* Vtw = (u16*)(ws + 40 * MB);     // [B][H][64][S]
  u16* Ow  = (u16*)(ws + 48 * MB);     // [B][S][1024] bf16 (8 MB)
  u16* maskb = (u16*)(ws + 56 * MB);   // 8 MB
  // phase-2 (attn) overlays on dead regions
  float* Op0  = (float*)(ws + 0 * MB);   // 16 MB over xb+yb
  float* Op1  = (float*)d_out;           // 16 MB; overwritten by out_gemm later
  float* denb = (float*)(ws + 16 * MB);  // 512 KB over wqb

  convert_all<<<16384, 256, 0, stream>>>(x, y, Wq, Wk, Wv, Wo, mask,
                                         xb, yb, wqb, wkb, wvb, wob, maskb);
  qkv_gemm<<<dim3(8, 32, 3), 256, 0, stream>>>(xb, yb, wqb, wkb, wvb, Qw, Kw, Vtw);
  attn_kernel<<<dim3(16, 16, 4), 256, 0, stream>>>(Qw, Kw, Vtw, maskb, Op0, Op1, denb);
  combine<<<4096, 256, 0, stream>>>(Op0, Op1, denb, Ow);
  out_gemm<<<dim3(8, 32), 256, 0, stream>>>(Ow, wob, (float*)d_out);
  (void)in_sizes; (void)n_in; (void)out_size; (void)ws_size;
}

// Round 5
// 261.898 us; speedup vs baseline: 1.1299x; 1.1299x over previous
//
#include <hip/hip_runtime.h>
#include <stdint.h>

typedef unsigned short u16;
typedef __attribute__((ext_vector_type(4))) float f32x4;
typedef __attribute__((ext_vector_type(2))) __bf16 bf16x2;
typedef __attribute__((ext_vector_type(8))) __bf16 bf16x8;
typedef __attribute__((ext_vector_type(4))) u16 u16x4;

#define AS1 __attribute__((address_space(1)))
#define AS3 __attribute__((address_space(3)))
#define GLOAD_LDS16(gp, lp) \
  __builtin_amdgcn_global_load_lds((const AS1 void*)(gp), (AS3 void*)(lp), 16, 0, 0)

__device__ __forceinline__ u16 f2bf(float f) {
  union { float f; unsigned u; } v; v.f = f;
  return (u16)((v.u + 0x7FFFu + ((v.u >> 16) & 1u)) >> 16);
}
__device__ __forceinline__ float bf2f(u16 u) {
  union { unsigned u; float f; } v; v.u = ((unsigned)u) << 16; return v.f;
}
__device__ __forceinline__ float fexp2(float x) {
#if __has_builtin(__builtin_amdgcn_exp2f)
  return __builtin_amdgcn_exp2f(x);
#else
  return exp2f(x);
#endif
}
__device__ __forceinline__ u16x4 pack4(float a, float b, float c, float d) {
#if __has_builtin(__builtin_amdgcn_cvt_pk_bf16_f32)
  union { struct { bf16x2 lo, hi; } p; u16x4 v; } u;
  u.p.lo = __builtin_amdgcn_cvt_pk_bf16_f32(a, b);
  u.p.hi = __builtin_amdgcn_cvt_pk_bf16_f32(c, d);
  return u.v;
#else
  u16x4 r; r.x = f2bf(a); r.y = f2bf(b); r.z = f2bf(c); r.w = f2bf(d); return r;
#endif
}

#define LOG2E 1.44269504f

// ---------- fp32 -> bf16 conversion ----------
__global__ __launch_bounds__(256) void convert_all(
    const float* __restrict__ x, const float* __restrict__ y,
    const float* __restrict__ wq, const float* __restrict__ wk,
    const float* __restrict__ wv, const float* __restrict__ wo,
    const float* __restrict__ mask,
    u16* __restrict__ xb, u16* __restrict__ yb, u16* __restrict__ wqb,
    u16* __restrict__ wkb, u16* __restrict__ wvb, u16* __restrict__ wob,
    u16* __restrict__ maskb) {
  size_t i = (size_t)blockIdx.x * 256 + threadIdx.x;  // float4 index, 4M total
  const float* src; u16* dst; float scale = 1.0f; size_t off;
  if (i < (size_t)(1u << 20)) { src = x; dst = xb; off = i; }
  else if (i < (size_t)(2u << 20)) { src = y; dst = yb; off = i - (1u << 20); }
  else if (i < (size_t)(3u << 20)) {
    size_t j = i - (size_t)(2u << 20);
    unsigned w = (unsigned)(j >> 18); off = j & ((1u << 18) - 1);
    if (w == 0)      { src = wq; dst = wqb; scale = 0.125f * LOG2E; }
    else if (w == 1) { src = wk; dst = wkb; }
    else if (w == 2) { src = wv; dst = wvb; }
    else             { src = wo; dst = wob; }
  } else { src = mask; dst = maskb; scale = LOG2E; off = i - (size_t)(3u << 20); }
  f32x4 v = ((const f32x4*)src)[off];
  ((u16x4*)dst)[off] = pack4(v.x * scale, v.y * scale, v.z * scale, v.w * scale);
}

// ---------- double-buffered BT-GEMM core: 128x128 tile, K=1024, BK=64 ----------
// As/Bs are 2 x 8192 u16 buffers. Stage(t+1) issued before compute(t); the
// barrier's vmcnt(0) then drains loads that overlapped a full compute phase.
__device__ __forceinline__ void gemm_core_db(
    const u16* __restrict__ A, const u16* __restrict__ Bt, int tm, int tn,
    u16* As, u16* Bs, f32x4 acc[4][4], int wave, int lane) {
  constexpr int K = 1024;
  const int l15 = lane & 15, quad = lane >> 4;
  const int wr = wave >> 1, wc = wave & 1;
  const int srow = lane >> 3;
  const int scol = ((lane & 7) ^ (srow & 7)) * 8;  // XOR-swizzled source colblk
  const u16* Ag = A + (size_t)(tm + wave * 32 + srow) * K + scol;
  const u16* Bg = Bt + (size_t)(tn + wave * 32 + srow) * K + scol;
  const int rsw = l15 & 7;

  // prologue: stage k-tile 0 into buffer 0
#pragma unroll
  for (int c = 0; c < 4; ++c) {
    GLOAD_LDS16(Ag + (size_t)c * 8 * K, &As[(wave * 4 + c) * 512]);
    GLOAD_LDS16(Bg + (size_t)c * 8 * K, &Bs[(wave * 4 + c) * 512]);
  }
  __syncthreads();

  for (int it = 0; it < 16; ++it) {
    const int cur = (it & 1) * 8192;
    const int nxt = 8192 - cur;
    if (it < 15) {
      const int k0 = (it + 1) * 64;
#pragma unroll
      for (int c = 0; c < 4; ++c) {
        GLOAD_LDS16(Ag + (size_t)c * 8 * K + k0, &As[nxt + (wave * 4 + c) * 512]);
        GLOAD_LDS16(Bg + (size_t)c * 8 * K + k0, &Bs[nxt + (wave * 4 + c) * 512]);
      }
    }
#pragma unroll
    for (int kq = 0; kq < 2; ++kq) {
      bf16x8 af[4], bfr[4];
#pragma unroll
      for (int mi = 0; mi < 4; ++mi)
        af[mi] = *(const bf16x8*)&As[cur + (wr * 64 + mi * 16 + l15) * 64 +
                                     ((kq * 4 + quad) ^ rsw) * 8];
#pragma unroll
      for (int ni = 0; ni < 4; ++ni)
        bfr[ni] = *(const bf16x8*)&Bs[cur + (wc * 64 + ni * 16 + l15) * 64 +
                                      ((kq * 4 + quad) ^ rsw) * 8];
#pragma unroll
      for (int mi = 0; mi < 4; ++mi)
#pragma unroll
        for (int ni = 0; ni < 4; ++ni)
          acc[mi][ni] = __builtin_amdgcn_mfma_f32_16x16x32_bf16(
              af[mi], bfr[ni], acc[mi][ni], 0, 0, 0);
    }
    __syncthreads();
  }
}

// ---------- fused Q/K/Vt projections ----------
__global__ __launch_bounds__(256, 2) void qkv_gemm(
    const u16* __restrict__ xb, const u16* __restrict__ yb,
    const u16* __restrict__ wqb, const u16* __restrict__ wkb,
    const u16* __restrict__ wvb,
    u16* __restrict__ Qw, u16* __restrict__ Kw, u16* __restrict__ Vtw) {
  __shared__ __align__(16) u16 As[2 * 128 * 64];
  __shared__ __align__(16) u16 Bs[2 * 128 * 64];
  const int tid = threadIdx.x, wave = tid >> 6, lane = tid & 63;
  const int l15 = lane & 15, quad = lane >> 4;
  const int wr = wave >> 1, wc = wave & 1;
  const int z = blockIdx.z;
  const u16 *A, *Bt; int tm, tn;
  if (z == 0)      { A = yb;  Bt = wqb; tm = blockIdx.y * 128; tn = blockIdx.x * 128; }
  else if (z == 1) { A = xb;  Bt = wkb; tm = blockIdx.y * 128; tn = blockIdx.x * 128; }
  else             { A = wvb; Bt = xb;  tm = blockIdx.x * 128; tn = blockIdx.y * 128; }

  f32x4 acc[4][4] = {};
  gemm_core_db(A, Bt, tm, tn, As, Bs, acc, wave, lane);

#pragma unroll
  for (int mi = 0; mi < 4; ++mi) {
#pragma unroll
    for (int ni = 0; ni < 4; ++ni) {
#pragma unroll
      for (int r = 0; r < 4; ++r) {
        int gm = tm + wr * 64 + mi * 16 + quad * 4 + r;
        int gn = tn + wc * 64 + ni * 16 + l15;
        u16 val = f2bf(acc[mi][ni][r]);
        if (z == 2) {  // Vt: [B][H][64][S]
          int h = gm >> 6, dh = gm & 63, b = gn >> 11, s = gn & 2047;
          Vtw[(((size_t)(b * 16 + h) * 64 + dh) << 11) + s] = val;
        } else {       // Q/K: [B][H][S][64]
          int b = gm >> 11, s = gm & 2047, h = gn >> 6, dh = gn & 63;
          u16* dst = (z == 0) ? Qw : Kw;
          dst[(((size_t)(b * 16 + h) * 2048 + s) << 6) + dh] = val;
        }
      }
    }
  }
}

// ---------- output projection: fp32 out ----------
__global__ __launch_bounds__(256, 2) void out_gemm(
    const u16* __restrict__ Ow, const u16* __restrict__ wob,
    float* __restrict__ C) {
  __shared__ __align__(16) u16 As[2 * 128 * 64];
  __shared__ __align__(16) u16 Bs[2 * 128 * 64];
  const int tid = threadIdx.x, wave = tid >> 6, lane = tid & 63;
  const int l15 = lane & 15, quad = lane >> 4;
  const int wr = wave >> 1, wc = wave & 1;
  const int tm = blockIdx.y * 128, tn = blockIdx.x * 128;

  f32x4 acc[4][4] = {};
  gemm_core_db(Ow, wob, tm, tn, As, Bs, acc, wave, lane);

#pragma unroll
  for (int mi = 0; mi < 4; ++mi)
#pragma unroll
    for (int ni = 0; ni < 4; ++ni)
#pragma unroll
      for (int r = 0; r < 4; ++r) {
        int gm = tm + wr * 64 + mi * 16 + quad * 4 + r;
        int gn = tn + wc * 64 + ni * 16 + l15;
        C[(size_t)gm * 1024 + gn] = acc[mi][ni][r];
      }
}

// ---------- flash-style attention v5: kt=64, double-buffered staging ----------
// 128 q/block, 4 waves x 32 q; grid (qt=16, h=16, b=2) = 512 blocks, 3/CU.
// Per iter: mask(t) loads issued FIRST (so exp's vmcnt wait doesn't drain the
// prefetch), then stage(t+1) gloads, then compute(t). Barrier drain overlaps
// a full compute phase. exp2 domain (Wq & mask pre-scaled by log2e).
__global__ __launch_bounds__(256, 3) void attn_kernel(
    const u16* __restrict__ Qw, const u16* __restrict__ Kw,
    const u16* __restrict__ Vtw, const u16* __restrict__ maskb,
    u16* __restrict__ Ow) {
  constexpr int S = 2048;
  constexpr int PADK = 72;                       // 144B rows; 2-way max on writes
  __shared__ __align__(16) u16 Ks[2 * 64 * 64];  // [key][dh] swizzled, 2 bufs
  __shared__ __align__(16) u16 Vs[2 * 64 * 64];  // [dh][key] swizzled, 2 bufs
  __shared__ __align__(16) u16 Ps[128 * PADK];   // [q][key] bf16 (wave-exclusive rows)
  const int tid = threadIdx.x;
  const int wave = tid >> 6, lane = tid & 63;
  const int l15 = lane & 15, quad = lane >> 4;
  const int qt = blockIdx.x, h = blockIdx.y, b = blockIdx.z;
  const size_t head = ((size_t)(b * 16 + h)) * S * 64;
  const int qbase = qt * 128 + wave * 32;        // wave owns 32 q-rows

  // Q B-frags in registers: B[n=q=l15][k=quad*8+j]  (pre-scaled by log2e/8)
  bf16x8 qf[2][2];
#pragma unroll
  for (int q2 = 0; q2 < 2; ++q2)
#pragma unroll
    for (int kq = 0; kq < 2; ++kq)
      qf[q2][kq] = *(const bf16x8*)&Qw[head +
          (size_t)(qbase + q2 * 16 + l15) * 64 + kq * 32 + quad * 8];

  const __bf16 one_bf = (__bf16)1.0f;
  const bf16x8 ones = {one_bf, one_bf, one_bf, one_bf, one_bf, one_bf, one_bf, one_bf};

  f32x4 oa[2][4] = {};
  f32x4 den[2] = {};

  // staging: chunk g = wave*2+c (1KB) = 8 rows x 128B; row g*8+(l>>3),
  // LDS slot l&7 <- global colblk (l&7)^(row&7)
  const int s_r = lane >> 3;
  const int s_c = ((lane & 7) ^ s_r) * 8;
  const int rsw = l15 & 7;

  // prologue: stage kt=0 into buffer 0
#pragma unroll
  for (int c = 0; c < 2; ++c) {
    int g = wave * 2 + c;
    GLOAD_LDS16(&Kw[head + (size_t)(g * 8 + s_r) * 64 + s_c], &Ks[g * 512]);
    GLOAD_LDS16(&Vtw[head + (size_t)(g * 8 + s_r) * S + s_c], &Vs[g * 512]);
  }
  __syncthreads();

  for (int it = 0; it < 32; ++it) {
    const int kt = it * 64;
    const int cur = (it & 1) * 4096;
    const int nxt = 4096 - cur;

    // mask loads for THIS iter (issued before the prefetch gloads)
    u16x4 mq[2][4];
#pragma unroll
    for (int q2 = 0; q2 < 2; ++q2)
#pragma unroll
      for (int mk = 0; mk < 4; ++mk)
        mq[q2][mk] = *(const u16x4*)&maskb[(size_t)(qbase + q2 * 16 + l15) * S +
                                           kt + mk * 16 + quad * 4];

    // stage NEXT k-tile into the other buffer
    if (it < 31) {
      const int kn = kt + 64;
#pragma unroll
      for (int c = 0; c < 2; ++c) {
        int g = wave * 2 + c;
        GLOAD_LDS16(&Kw[head + (size_t)(kn + g * 8 + s_r) * 64 + s_c],
                    &Ks[nxt + g * 512]);
        GLOAD_LDS16(&Vtw[head + (size_t)(g * 8 + s_r) * S + kn + s_c],
                    &Vs[nxt + g * 512]);
      }
    }

    // S^T = K·Q^T : m=key (4 tiles), n=query (2 tiles)
    f32x4 sa[2][4] = {};
#pragma unroll
    for (int kq = 0; kq < 2; ++kq) {
#pragma unroll
      for (int mk = 0; mk < 4; ++mk) {
        bf16x8 ak = *(const bf16x8*)&Ks[cur + (mk * 16 + l15) * 64 +
                                        ((kq * 4 + quad) ^ rsw) * 8];
        sa[0][mk] = __builtin_amdgcn_mfma_f32_16x16x32_bf16(ak, qf[0][kq], sa[0][mk], 0, 0, 0);
        sa[1][mk] = __builtin_amdgcn_mfma_f32_16x16x32_bf16(ak, qf[1][kq], sa[1][mk], 0, 0, 0);
      }
    }

    // P = exp2(S + mask) -> Ps (wave-exclusive rows; no barrier needed)
#pragma unroll
    for (int q2 = 0; q2 < 2; ++q2) {
#pragma unroll
      for (int mk = 0; mk < 4; ++mk) {
        float p0 = fexp2(sa[q2][mk][0] + bf2f(mq[q2][mk].x));
        float p1 = fexp2(sa[q2][mk][1] + bf2f(mq[q2][mk].y));
        float p2 = fexp2(sa[q2][mk][2] + bf2f(mq[q2][mk].z));
        float p3 = fexp2(sa[q2][mk][3] + bf2f(mq[q2][mk].w));
        *(u16x4*)&Ps[(wave * 32 + q2 * 16 + l15) * PADK + mk * 16 + quad * 4] =
            pack4(p0, p1, p2, p3);
      }
    }

    // O += P·V ; den += P·1
#pragma unroll
    for (int kq2 = 0; kq2 < 2; ++kq2) {
      bf16x8 ap0 = *(const bf16x8*)&Ps[(wave * 32 + l15) * PADK + kq2 * 32 + quad * 8];
      bf16x8 ap1 = *(const bf16x8*)&Ps[(wave * 32 + 16 + l15) * PADK + kq2 * 32 + quad * 8];
#pragma unroll
      for (int nv = 0; nv < 4; ++nv) {
        bf16x8 bv = *(const bf16x8*)&Vs[cur + (nv * 16 + l15) * 64 +
                                        ((kq2 * 4 + quad) ^ rsw) * 8];
        oa[0][nv] = __builtin_amdgcn_mfma_f32_16x16x32_bf16(ap0, bv, oa[0][nv], 0, 0, 0);
        oa[1][nv] = __builtin_amdgcn_mfma_f32_16x16x32_bf16(ap1, bv, oa[1][nv], 0, 0, 0);
      }
      den[0] = __builtin_amdgcn_mfma_f32_16x16x32_bf16(ap0, ones, den[0], 0, 0, 0);
      den[1] = __builtin_amdgcn_mfma_f32_16x16x32_bf16(ap1, ones, den[1], 0, 0, 0);
    }
    __syncthreads();  // drains stage(t+1) loads, which overlapped this compute
  }

  // epilogue: O / (den + 1e-10) -> Ow [B][S][H*64] bf16
#pragma unroll
  for (int q2 = 0; q2 < 2; ++q2) {
#pragma unroll
    for (int nv = 0; nv < 4; ++nv) {
#pragma unroll
      for (int r = 0; r < 4; ++r) {
        int srow = qbase + q2 * 16 + quad * 4 + r;
        int dh = nv * 16 + l15;
        float val = oa[q2][nv][r] / (den[q2][r] + 1e-10f);
        Ow[((size_t)(b * S + srow) << 10) + h * 64 + dh] = f2bf(val);
      }
    }
  }
}

extern "C" void kernel_launch(void* const* d_in, const int* in_sizes, int n_in,
                              void* d_out, int out_size, void* d_ws, size_t ws_size,
                              hipStream_t stream) {
  const float* x    = (const float*)d_in[0];
  const float* y    = (const float*)d_in[1];
  const float* mask = (const float*)d_in[2];
  const float* Wq   = (const float*)d_in[3];
  const float* Wk   = (const float*)d_in[4];
  const float* Wv   = (const float*)d_in[5];
  const float* Wo   = (const float*)d_in[6];
  char* ws = (char*)d_ws;
  const size_t MB = (size_t)1 << 20;
  u16* xb  = (u16*)(ws + 0  * MB);
  u16* yb  = (u16*)(ws + 8  * MB);
  u16* wqb = (u16*)(ws + 16 * MB);
  u16* wkb = (u16*)(ws + 18 * MB);
  u16* wvb = (u16*)(ws + 20 * MB);
  u16* wob = (u16*)(ws + 22 * MB);
  u16* Qw  = (u16*)(ws + 24 * MB);   // [B][H][S][64] bf16, scaled log2e/8
  u16* Kw  = (u16*)(ws + 32 * MB);
  u16* Vtw = (u16*)(ws + 40 * MB);   // [B][H][64][S]
  u16* Ow  = (u16*)(ws + 48 * MB);   // [B][S][1024] bf16
  u16* maskb = (u16*)(ws + 56 * MB); // [S][S] bf16, pre-scaled log2e

  convert_all<<<16384, 256, 0, stream>>>(x, y, Wq, Wk, Wv, Wo, mask,
                                         xb, yb, wqb, wkb, wvb, wob, maskb);
  qkv_gemm<<<dim3(8, 32, 3), 256, 0, stream>>>(xb, yb, wqb, wkb, wvb, Qw, Kw, Vtw);
  attn_kernel<<<dim3(16, 16, 2), 256, 0, stream>>>(Qw, Kw, Vtw, maskb, Ow);
  out_gemm<<<dim3(8, 32), 256, 0, stream>>>(Ow, wob, (float*)d_out);
  (void)in_sizes; (void)n_in; (void)out_size; (void)ws_size;
}

// Round 6
// 238.928 us; speedup vs baseline: 1.2386x; 1.0961x over previous
//
#include <hip/hip_runtime.h>
#include <stdint.h>

typedef unsigned short u16;
typedef __attribute__((ext_vector_type(4))) float f32x4;
typedef __attribute__((ext_vector_type(2))) __bf16 bf16x2;
typedef __attribute__((ext_vector_type(8))) __bf16 bf16x8;
typedef __attribute__((ext_vector_type(4))) u16 u16x4;

#define AS1 __attribute__((address_space(1)))
#define AS3 __attribute__((address_space(3)))
#define GLOAD_LDS16(gp, lp) \
  __builtin_amdgcn_global_load_lds((const AS1 void*)(gp), (AS3 void*)(lp), 16, 0, 0)

__device__ __forceinline__ u16 f2bf(float f) {
  union { float f; unsigned u; } v; v.f = f;
  return (u16)((v.u + 0x7FFFu + ((v.u >> 16) & 1u)) >> 16);
}
__device__ __forceinline__ float bf2f(u16 u) {
  union { unsigned u; float f; } v; v.u = ((unsigned)u) << 16; return v.f;
}
__device__ __forceinline__ float fexp2(float x) {
#if __has_builtin(__builtin_amdgcn_exp2f)
  return __builtin_amdgcn_exp2f(x);
#else
  return exp2f(x);
#endif
}
__device__ __forceinline__ u16x4 pack4(float a, float b, float c, float d) {
#if __has_builtin(__builtin_amdgcn_cvt_pk_bf16_f32)
  union { struct { bf16x2 lo, hi; } p; u16x4 v; } u;
  u.p.lo = __builtin_amdgcn_cvt_pk_bf16_f32(a, b);
  u.p.hi = __builtin_amdgcn_cvt_pk_bf16_f32(c, d);
  return u.v;
#else
  u16x4 r; r.x = f2bf(a); r.y = f2bf(b); r.z = f2bf(c); r.w = f2bf(d); return r;
#endif
}

#define LOG2E 1.44269504f

// ---------- fp32 -> bf16 conversion ----------
__global__ __launch_bounds__(256) void convert_all(
    const float* __restrict__ x, const float* __restrict__ y,
    const float* __restrict__ wq, const float* __restrict__ wk,
    const float* __restrict__ wv, const float* __restrict__ wo,
    const float* __restrict__ mask,
    u16* __restrict__ xb, u16* __restrict__ yb, u16* __restrict__ wqb,
    u16* __restrict__ wkb, u16* __restrict__ wvb, u16* __restrict__ wob,
    u16* __restrict__ maskb) {
  size_t i = (size_t)blockIdx.x * 256 + threadIdx.x;  // float4 index, 4M total
  const float* src; u16* dst; float scale = 1.0f; size_t off;
  if (i < (size_t)(1u << 20)) { src = x; dst = xb; off = i; }
  else if (i < (size_t)(2u << 20)) { src = y; dst = yb; off = i - (1u << 20); }
  else if (i < (size_t)(3u << 20)) {
    size_t j = i - (size_t)(2u << 20);
    unsigned w = (unsigned)(j >> 18); off = j & ((1u << 18) - 1);
    if (w == 0)      { src = wq; dst = wqb; scale = 0.125f * LOG2E; }
    else if (w == 1) { src = wk; dst = wkb; }
    else if (w == 2) { src = wv; dst = wvb; }
    else             { src = wo; dst = wob; }
  } else { src = mask; dst = maskb; scale = LOG2E; off = i - (size_t)(3u << 20); }
  f32x4 v = ((const f32x4*)src)[off];
  ((u16x4*)dst)[off] = pack4(v.x * scale, v.y * scale, v.z * scale, v.w * scale);
}

// ---------- BT-GEMM core (R3): 128x128 tile, K=1024, BK=64, XOR-swizzled ----------
__device__ __forceinline__ void gemm_core64(
    const u16* __restrict__ A, const u16* __restrict__ Bt, int tm, int tn,
    u16* As, u16* Bs, f32x4 acc[4][4], int wave, int lane) {
  constexpr int K = 1024;
  const int l15 = lane & 15, quad = lane >> 4;
  const int wr = wave >> 1, wc = wave & 1;
  const int srow = lane >> 3;
  const int scol = ((lane & 7) ^ (srow & 7)) * 8;
  const u16* Ag = A + (size_t)(tm + wave * 32 + srow) * K + scol;
  const u16* Bg = Bt + (size_t)(tn + wave * 32 + srow) * K + scol;
  const int rsw = l15 & 7;

  for (int k0 = 0; k0 < K; k0 += 64) {
    __syncthreads();
#pragma unroll
    for (int c = 0; c < 4; ++c)
      GLOAD_LDS16(Ag + (size_t)c * 8 * K + k0, &As[(wave * 4 + c) * 512]);
#pragma unroll
    for (int c = 0; c < 4; ++c)
      GLOAD_LDS16(Bg + (size_t)c * 8 * K + k0, &Bs[(wave * 4 + c) * 512]);
    __syncthreads();
#pragma unroll
    for (int kq = 0; kq < 2; ++kq) {
      bf16x8 af[4], bfr[4];
#pragma unroll
      for (int mi = 0; mi < 4; ++mi)
        af[mi] = *(const bf16x8*)&As[(wr * 64 + mi * 16 + l15) * 64 +
                                     ((kq * 4 + quad) ^ rsw) * 8];
#pragma unroll
      for (int ni = 0; ni < 4; ++ni)
        bfr[ni] = *(const bf16x8*)&Bs[(wc * 64 + ni * 16 + l15) * 64 +
                                      ((kq * 4 + quad) ^ rsw) * 8];
#pragma unroll
      for (int mi = 0; mi < 4; ++mi)
#pragma unroll
        for (int ni = 0; ni < 4; ++ni)
          acc[mi][ni] = __builtin_amdgcn_mfma_f32_16x16x32_bf16(
              af[mi], bfr[ni], acc[mi][ni], 0, 0, 0);
    }
  }
}

// ---------- fused Q/K/Vt projections ----------
__global__ __launch_bounds__(256, 3) void qkv_gemm(
    const u16* __restrict__ xb, const u16* __restrict__ yb,
    const u16* __restrict__ wqb, const u16* __restrict__ wkb,
    const u16* __restrict__ wvb,
    u16* __restrict__ Qw, u16* __restrict__ Kw, u16* __restrict__ Vtw) {
  __shared__ __align__(16) u16 As[128 * 64];
  __shared__ __align__(16) u16 Bs[128 * 64];
  const int tid = threadIdx.x, wave = tid >> 6, lane = tid & 63;
  const int l15 = lane & 15, quad = lane >> 4;
  const int wr = wave >> 1, wc = wave & 1;
  const int z = blockIdx.z;
  const u16 *A, *Bt; int tm, tn;
  if (z == 0)      { A = yb;  Bt = wqb; tm = blockIdx.y * 128; tn = blockIdx.x * 128; }
  else if (z == 1) { A = xb;  Bt = wkb; tm = blockIdx.y * 128; tn = blockIdx.x * 128; }
  else             { A = wvb; Bt = xb;  tm = blockIdx.x * 128; tn = blockIdx.y * 128; }

  f32x4 acc[4][4] = {};
  gemm_core64(A, Bt, tm, tn, As, Bs, acc, wave, lane);

#pragma unroll
  for (int mi = 0; mi < 4; ++mi) {
#pragma unroll
    for (int ni = 0; ni < 4; ++ni) {
#pragma unroll
      for (int r = 0; r < 4; ++r) {
        int gm = tm + wr * 64 + mi * 16 + quad * 4 + r;
        int gn = tn + wc * 64 + ni * 16 + l15;
        u16 val = f2bf(acc[mi][ni][r]);
        if (z == 2) {  // Vt: [B][H][64][S]
          int h = gm >> 6, dh = gm & 63, b = gn >> 11, s = gn & 2047;
          Vtw[(((size_t)(b * 16 + h) * 64 + dh) << 11) + s] = val;
        } else {       // Q/K: [B][H][S][64]
          int b = gm >> 11, s = gm & 2047, h = gn >> 6, dh = gn & 63;
          u16* dst = (z == 0) ? Qw : Kw;
          dst[(((size_t)(b * 16 + h) * 2048 + s) << 6) + dh] = val;
        }
      }
    }
  }
}

// ---------- output projection: 64x128 tiles (512 blocks, 2/CU) ----------
__global__ __launch_bounds__(256, 3) void out_gemm(
    const u16* __restrict__ Ow, const u16* __restrict__ wob,
    float* __restrict__ C) {
  constexpr int K = 1024;
  __shared__ __align__(16) u16 As[64 * 64];
  __shared__ __align__(16) u16 Bs[128 * 64];
  const int tid = threadIdx.x, wave = tid >> 6, lane = tid & 63;
  const int l15 = lane & 15, quad = lane >> 4;
  const int wr = wave >> 1, wc = wave & 1;
  const int tm = blockIdx.y * 64, tn = blockIdx.x * 128;
  const int srow = lane >> 3;
  const int scol = ((lane & 7) ^ (srow & 7)) * 8;
  const u16* Ag = Ow + (size_t)(tm + wave * 16 + srow) * K + scol;
  const u16* Bg = wob + (size_t)(tn + wave * 32 + srow) * K + scol;
  const int rsw = l15 & 7;

  f32x4 acc[2][4] = {};
  for (int k0 = 0; k0 < K; k0 += 64) {
    __syncthreads();
#pragma unroll
    for (int c = 0; c < 2; ++c)
      GLOAD_LDS16(Ag + (size_t)c * 8 * K + k0, &As[(wave * 2 + c) * 512]);
#pragma unroll
    for (int c = 0; c < 4; ++c)
      GLOAD_LDS16(Bg + (size_t)c * 8 * K + k0, &Bs[(wave * 4 + c) * 512]);
    __syncthreads();
#pragma unroll
    for (int kq = 0; kq < 2; ++kq) {
      bf16x8 af[2], bfr[4];
#pragma unroll
      for (int mi = 0; mi < 2; ++mi)
        af[mi] = *(const bf16x8*)&As[(wr * 32 + mi * 16 + l15) * 64 +
                                     ((kq * 4 + quad) ^ rsw) * 8];
#pragma unroll
      for (int ni = 0; ni < 4; ++ni)
        bfr[ni] = *(const bf16x8*)&Bs[(wc * 64 + ni * 16 + l15) * 64 +
                                      ((kq * 4 + quad) ^ rsw) * 8];
#pragma unroll
      for (int mi = 0; mi < 2; ++mi)
#pragma unroll
        for (int ni = 0; ni < 4; ++ni)
          acc[mi][ni] = __builtin_amdgcn_mfma_f32_16x16x32_bf16(
              af[mi], bfr[ni], acc[mi][ni], 0, 0, 0);
    }
  }

#pragma unroll
  for (int mi = 0; mi < 2; ++mi)
#pragma unroll
    for (int ni = 0; ni < 4; ++ni)
#pragma unroll
      for (int r = 0; r < 4; ++r) {
        int gm = tm + wr * 32 + mi * 16 + quad * 4 + r;
        int gn = tn + wc * 64 + ni * 16 + l15;
        C[(size_t)gm * 1024 + gn] = acc[mi][ni][r];
      }
}

// ---------- attention v6: ZERO block barriers in main loop ----------
// Block = 128 q x full 2048 keys; wave w owns (q-half = w>>1, key-half = w&1):
// 64 q-rows x 1024 keys, wave-PRIVATE dbuf K/V LDS tiles (kt=32) + private P.
// Only wave-local s_waitcnt(0) per iter -> waves phase-skew, MFMA/VALU overlap.
// One __syncthreads at end; odd waves combine partner's f32 partials from LDS.
__global__ __launch_bounds__(256, 2) void attn_kernel(
    const u16* __restrict__ Qw, const u16* __restrict__ Kw,
    const u16* __restrict__ Vtw, const u16* __restrict__ maskb,
    u16* __restrict__ Ow) {
  constexpr int S = 2048;
  __shared__ __align__(16) u16 KV[4][2][4096];  // /wave /buf: K[32k][64dh] | V[64dh][32k]
  __shared__ __align__(16) u16 Pbuf[4][2048];   // /wave: P[64 q][32 k] bf16
  const int tid = threadIdx.x;
  const int wave = tid >> 6, lane = tid & 63;
  const int l15 = lane & 15, quad = lane >> 4;
  const int h = blockIdx.y, b = blockIdx.z;
  const size_t head = ((size_t)(b * 16 + h)) * S * 64;
  const int qbase = blockIdx.x * 128 + (wave >> 1) * 64;  // wave's 64 q-rows
  const int kwb = (wave & 1) * 1024;                      // wave's key-half

  // Q B-frags: B[n=q=l15][k=dh]; Qw pre-scaled by log2e/8
  bf16x8 qf[4][2];
#pragma unroll
  for (int qt = 0; qt < 4; ++qt)
#pragma unroll
    for (int kq = 0; kq < 2; ++kq)
      qf[qt][kq] = *(const bf16x8*)&Qw[head +
          (size_t)(qbase + qt * 16 + l15) * 64 + kq * 32 + quad * 8];

  const __bf16 one_bf = (__bf16)1.0f;
  const bf16x8 ones = {one_bf, one_bf, one_bf, one_bf, one_bf, one_bf, one_bf, one_bf};

  f32x4 oa[4][4] = {};
  f32x4 den[4] = {};
  u16x4 mq[2][4][2];

  const int k_r = lane >> 3;                       // K staging row-in-chunk
  const int k_c = ((lane & 7) ^ k_r) * 8;          // swizzled colblk (128B rows)
  const int v_r = lane >> 2;                       // V staging row-in-chunk
  const int v_c = (lane & 3) * 8;                  // 64B rows: no swizzle needed
  const int rsw = l15 & 7;
  u16* Ps = &Pbuf[wave][0];

  // stage tile 0 + mask 0 into buf/set 0
#pragma unroll
  for (int c = 0; c < 4; ++c)
    GLOAD_LDS16(&Kw[head + (size_t)(kwb + c * 8 + k_r) * 64 + k_c], &KV[wave][0][c * 512]);
#pragma unroll
  for (int c = 0; c < 4; ++c)
    GLOAD_LDS16(&Vtw[head + (size_t)(c * 16 + v_r) * S + kwb + v_c], &KV[wave][0][2048 + c * 512]);
#pragma unroll
  for (int qt = 0; qt < 4; ++qt)
#pragma unroll
    for (int mk = 0; mk < 2; ++mk)
      mq[0][qt][mk] = *(const u16x4*)&maskb[(size_t)(qbase + qt * 16 + l15) * S +
                                            kwb + mk * 16 + quad * 4];

#pragma unroll 1
  for (int itb = 0; itb < 16; ++itb) {
#pragma unroll
    for (int half = 0; half < 2; ++half) {
      const int it = itb * 2 + half;
      __builtin_amdgcn_s_waitcnt(0);  // wave-local: drains loads issued LAST iter

      // prefetch tile it+1 into other buf/mask set
      if (it < 31) {
        const int ko = kwb + (it + 1) * 32;
#pragma unroll
        for (int c = 0; c < 4; ++c)
          GLOAD_LDS16(&Kw[head + (size_t)(ko + c * 8 + k_r) * 64 + k_c],
                      &KV[wave][half ^ 1][c * 512]);
#pragma unroll
        for (int c = 0; c < 4; ++c)
          GLOAD_LDS16(&Vtw[head + (size_t)(c * 16 + v_r) * S + ko + v_c],
                      &KV[wave][half ^ 1][2048 + c * 512]);
#pragma unroll
        for (int qt = 0; qt < 4; ++qt)
#pragma unroll
          for (int mk = 0; mk < 2; ++mk)
            mq[half ^ 1][qt][mk] = *(const u16x4*)&maskb[
                (size_t)(qbase + qt * 16 + l15) * S + ko + mk * 16 + quad * 4];
      }

      const u16* Ks = &KV[wave][half][0];
      const u16* Vs = &KV[wave][half][2048];

      // S^T = K·Q^T : D[m=key][n=q]; 2 key-tiles x 4 q-tiles
      f32x4 sa[4][2] = {};
#pragma unroll
      for (int kq = 0; kq < 2; ++kq) {
#pragma unroll
        for (int mk = 0; mk < 2; ++mk) {
          bf16x8 ak = *(const bf16x8*)&Ks[(mk * 16 + l15) * 64 +
                                          ((kq * 4 + quad) ^ rsw) * 8];
#pragma unroll
          for (int qt = 0; qt < 4; ++qt)
            sa[qt][mk] = __builtin_amdgcn_mfma_f32_16x16x32_bf16(
                ak, qf[qt][kq], sa[qt][mk], 0, 0, 0);
        }
      }

      // P = exp2(S + mask) -> wave-private Ps
#pragma unroll
      for (int qt = 0; qt < 4; ++qt) {
#pragma unroll
        for (int mk = 0; mk < 2; ++mk) {
          float p0 = fexp2(sa[qt][mk][0] + bf2f(mq[half][qt][mk].x));
          float p1 = fexp2(sa[qt][mk][1] + bf2f(mq[half][qt][mk].y));
          float p2 = fexp2(sa[qt][mk][2] + bf2f(mq[half][qt][mk].z));
          float p3 = fexp2(sa[qt][mk][3] + bf2f(mq[half][qt][mk].w));
          *(u16x4*)&Ps[(qt * 16 + l15) * 32 + mk * 16 + quad * 4] =
              pack4(p0, p1, p2, p3);
        }
      }

      // O += P·V ; den += P·1   (K=32: single PV step)
#pragma unroll
      for (int qt = 0; qt < 4; ++qt) {
        bf16x8 ap = *(const bf16x8*)&Ps[(qt * 16 + l15) * 32 + quad * 8];
#pragma unroll
        for (int nv = 0; nv < 4; ++nv) {
          bf16x8 bv = *(const bf16x8*)&Vs[(nv * 16 + l15) * 32 + quad * 8];
          oa[qt][nv] = __builtin_amdgcn_mfma_f32_16x16x32_bf16(
              ap, bv, oa[qt][nv], 0, 0, 0);
        }
        den[qt] = __builtin_amdgcn_mfma_f32_16x16x32_bf16(ap, ones, den[qt], 0, 0, 0);
      }
    }
  }

  // ---- combine: even waves publish partials; odd waves add own + store ----
  __builtin_amdgcn_s_waitcnt(0);
  if (!(wave & 1)) {
    float* osc = (float*)&KV[wave][0][0];   // 4096 f32 = 16 KB
    float* dsc = (float*)&Pbuf[wave][0];    // 1024 f32
#pragma unroll
    for (int qt = 0; qt < 4; ++qt) {
#pragma unroll
      for (int nv = 0; nv < 4; ++nv)
        *(f32x4*)&osc[(qt * 4 + nv) * 256 + lane * 4] = oa[qt][nv];
      *(f32x4*)&dsc[qt * 256 + lane * 4] = den[qt];
    }
  }
  __syncthreads();
  if (wave & 1) {
    const float* posc = (const float*)&KV[wave - 1][0][0];
    const float* pdsc = (const float*)&Pbuf[wave - 1][0];
#pragma unroll
    for (int qt = 0; qt < 4; ++qt) {
      f32x4 dsum = *(const f32x4*)&pdsc[qt * 256 + lane * 4];
      f32x4 rd;
#pragma unroll
      for (int r = 0; r < 4; ++r)
        rd[r] = __builtin_amdgcn_rcpf(dsum[r] + den[qt][r] + 1e-10f);
#pragma unroll
      for (int nv = 0; nv < 4; ++nv) {
        f32x4 po = *(const f32x4*)&posc[(qt * 4 + nv) * 256 + lane * 4];
#pragma unroll
        for (int r = 0; r < 4; ++r) {
          int q = qbase + qt * 16 + quad * 4 + r;
          int dh = nv * 16 + l15;
          Ow[((size_t)(b * S + q) << 10) + h * 64 + dh] =
              f2bf((po[r] + oa[qt][nv][r]) * rd[r]);
        }
      }
    }
  }
}

extern "C" void kernel_launch(void* const* d_in, const int* in_sizes, int n_in,
                              void* d_out, int out_size, void* d_ws, size_t ws_size,
                              hipStream_t stream) {
  const float* x    = (const float*)d_in[0];
  const float* y    = (const float*)d_in[1];
  const float* mask = (const float*)d_in[2];
  const float* Wq   = (const float*)d_in[3];
  const float* Wk   = (const float*)d_in[4];
  const float* Wv   = (const float*)d_in[5];
  const float* Wo   = (const float*)d_in[6];
  char* ws = (char*)d_ws;
  const size_t MB = (size_t)1 << 20;
  u16* xb  = (u16*)(ws + 0  * MB);
  u16* yb  = (u16*)(ws + 8  * MB);
  u16* wqb = (u16*)(ws + 16 * MB);
  u16* wkb = (u16*)(ws + 18 * MB);
  u16* wvb = (u16*)(ws + 20 * MB);
  u16* wob = (u16*)(ws + 22 * MB);
  u16* Qw  = (u16*)(ws + 24 * MB);   // [B][H][S][64] bf16, scaled log2e/8
  u16* Kw  = (u16*)(ws + 32 * MB);
  u16* Vtw = (u16*)(ws + 40 * MB);   // [B][H][64][S]
  u16* Ow  = (u16*)(ws + 48 * MB);   // [B][S][1024] bf16
  u16* maskb = (u16*)(ws + 56 * MB); // [S][S] bf16, pre-scaled log2e

  convert_all<<<16384, 256, 0, stream>>>(x, y, Wq, Wk, Wv, Wo, mask,
                                         xb, yb, wqb, wkb, wvb, wob, maskb);
  qkv_gemm<<<dim3(8, 32, 3), 256, 0, stream>>>(xb, yb, wqb, wkb, wvb, Qw, Kw, Vtw);
  attn_kernel<<<dim3(16, 16, 2), 256, 0, stream>>>(Qw, Kw, Vtw, maskb, Ow);
  out_gemm<<<dim3(8, 64), 256, 0, stream>>>(Ow, wob, (float*)d_out);
  (void)in_sizes; (void)n_in; (void)out_size; (void)ws_size;
}

// Round 8
// 233.724 us; speedup vs baseline: 1.2661x; 1.0223x over previous
//
#include <hip/hip_runtime.h>
#include <stdint.h>

typedef unsigned short u16;
typedef __attribute__((ext_vector_type(4))) float f32x4;
typedef __attribute__((ext_vector_type(2))) __bf16 bf16x2;
typedef __attribute__((ext_vector_type(8))) __bf16 bf16x8;
typedef __attribute__((ext_vector_type(4))) u16 u16x4;
typedef __attribute__((ext_vector_type(2))) _Float16 f16x2;
typedef __attribute__((ext_vector_type(4))) _Float16 f16x4;

#define AS1 __attribute__((address_space(1)))
#define AS3 __attribute__((address_space(3)))
#define GLOAD_LDS16(gp, lp) \
  __builtin_amdgcn_global_load_lds((const AS1 void*)(gp), (AS3 void*)(lp), 16, 0, 0)

__device__ __forceinline__ u16 f2bf(float f) {
  union { float f; unsigned u; } v; v.f = f;
  return (u16)((v.u + 0x7FFFu + ((v.u >> 16) & 1u)) >> 16);
}
__device__ __forceinline__ u16 f2h(float f) {
  union { _Float16 h; u16 u; } v; v.h = (_Float16)f; return v.u;
}
__device__ __forceinline__ float bf2f(u16 u) {
  union { unsigned u; float f; } v; v.u = ((unsigned)u) << 16; return v.f;
}
__device__ __forceinline__ float fexp2(float x) {
#if __has_builtin(__builtin_amdgcn_exp2f)
  return __builtin_amdgcn_exp2f(x);
#else
  return exp2f(x);
#endif
}
__device__ __forceinline__ f16x2 pkf16(float a, float b) {
#if __has_builtin(__builtin_amdgcn_cvt_pkrtz)
  return __builtin_bit_cast(f16x2, __builtin_amdgcn_cvt_pkrtz(a, b));
#else
  f16x2 r; r.x = (_Float16)a; r.y = (_Float16)b; return r;
#endif
}
__device__ __forceinline__ u16x4 pack4(float a, float b, float c, float d) {
#if __has_builtin(__builtin_amdgcn_cvt_pk_bf16_f32)
  union { struct { bf16x2 lo, hi; } p; u16x4 v; } u;
  u.p.lo = __builtin_amdgcn_cvt_pk_bf16_f32(a, b);
  u.p.hi = __builtin_amdgcn_cvt_pk_bf16_f32(c, d);
  return u.v;
#else
  u16x4 r; r.x = f2bf(a); r.y = f2bf(b); r.z = f2bf(c); r.w = f2bf(d); return r;
#endif
}

#define LOG2E 1.44269504f

// ---------- fp32 -> bf16 conversion ----------
__global__ __launch_bounds__(256) void convert_all(
    const float* __restrict__ x, const float* __restrict__ y,
    const float* __restrict__ wq, const float* __restrict__ wk,
    const float* __restrict__ wv, const float* __restrict__ wo,
    const float* __restrict__ mask,
    u16* __restrict__ xb, u16* __restrict__ yb, u16* __restrict__ wqb,
    u16* __restrict__ wkb, u16* __restrict__ wvb, u16* __restrict__ wob,
    u16* __restrict__ maskb) {
  size_t i = (size_t)blockIdx.x * 256 + threadIdx.x;  // float4 index, 4M total
  const float* src; u16* dst; float scale = 1.0f; size_t off;
  if (i < (size_t)(1u << 20)) { src = x; dst = xb; off = i; }
  else if (i < (size_t)(2u << 20)) { src = y; dst = yb; off = i - (1u << 20); }
  else if (i < (size_t)(3u << 20)) {
    size_t j = i - (size_t)(2u << 20);
    unsigned w = (unsigned)(j >> 18); off = j & ((1u << 18) - 1);
    if (w == 0)      { src = wq; dst = wqb; scale = 0.125f * LOG2E; }
    else if (w == 1) { src = wk; dst = wkb; }
    else if (w == 2) { src = wv; dst = wvb; }
    else             { src = wo; dst = wob; }
  } else { src = mask; dst = maskb; scale = LOG2E; off = i - (size_t)(3u << 20); }
  f32x4 v = ((const f32x4*)src)[off];
  ((u16x4*)dst)[off] = pack4(v.x * scale, v.y * scale, v.z * scale, v.w * scale);
}

// ---------- BT-GEMM core: 128x128 tile, K=1024, BK=64, XOR-swizzled ----------
__device__ __forceinline__ void gemm_core64(
    const u16* __restrict__ A, const u16* __restrict__ Bt, int tm, int tn,
    u16* As, u16* Bs, f32x4 acc[4][4], int wave, int lane) {
  constexpr int K = 1024;
  const int l15 = lane & 15, quad = lane >> 4;
  const int wr = wave >> 1, wc = wave & 1;
  const int srow = lane >> 3;
  const int scol = ((lane & 7) ^ (srow & 7)) * 8;
  const u16* Ag = A + (size_t)(tm + wave * 32 + srow) * K + scol;
  const u16* Bg = Bt + (size_t)(tn + wave * 32 + srow) * K + scol;
  const int rsw = l15 & 7;

  for (int k0 = 0; k0 < K; k0 += 64) {
    __syncthreads();
#pragma unroll
    for (int c = 0; c < 4; ++c)
      GLOAD_LDS16(Ag + (size_t)c * 8 * K + k0, &As[(wave * 4 + c) * 512]);
#pragma unroll
    for (int c = 0; c < 4; ++c)
      GLOAD_LDS16(Bg + (size_t)c * 8 * K + k0, &Bs[(wave * 4 + c) * 512]);
    __syncthreads();
#pragma unroll
    for (int kq = 0; kq < 2; ++kq) {
      bf16x8 af[4], bfr[4];
#pragma unroll
      for (int mi = 0; mi < 4; ++mi)
        af[mi] = *(const bf16x8*)&As[(wr * 64 + mi * 16 + l15) * 64 +
                                     ((kq * 4 + quad) ^ rsw) * 8];
#pragma unroll
      for (int ni = 0; ni < 4; ++ni)
        bfr[ni] = *(const bf16x8*)&Bs[(wc * 64 + ni * 16 + l15) * 64 +
                                      ((kq * 4 + quad) ^ rsw) * 8];
#pragma unroll
      for (int mi = 0; mi < 4; ++mi)
#pragma unroll
        for (int ni = 0; ni < 4; ++ni)
          acc[mi][ni] = __builtin_amdgcn_mfma_f32_16x16x32_bf16(
              af[mi], bfr[ni], acc[mi][ni], 0, 0, 0);
    }
  }
}

// ---------- fused Q/K/Vt projections (Vt written as f16) ----------
__global__ __launch_bounds__(256, 3) void qkv_gemm(
    const u16* __restrict__ xb, const u16* __restrict__ yb,
    const u16* __restrict__ wqb, const u16* __restrict__ wkb,
    const u16* __restrict__ wvb,
    u16* __restrict__ Qw, u16* __restrict__ Kw, u16* __restrict__ Vtw) {
  __shared__ __align__(16) u16 As[128 * 64];
  __shared__ __align__(16) u16 Bs[128 * 64];
  const int tid = threadIdx.x, wave = tid >> 6, lane = tid & 63;
  const int l15 = lane & 15, quad = lane >> 4;
  const int wr = wave >> 1, wc = wave & 1;
  const int z = blockIdx.z;
  const u16 *A, *Bt; int tm, tn;
  if (z == 0)      { A = yb;  Bt = wqb; tm = blockIdx.y * 128; tn = blockIdx.x * 128; }
  else if (z == 1) { A = xb;  Bt = wkb; tm = blockIdx.y * 128; tn = blockIdx.x * 128; }
  else             { A = wvb; Bt = xb;  tm = blockIdx.x * 128; tn = blockIdx.y * 128; }

  f32x4 acc[4][4] = {};
  gemm_core64(A, Bt, tm, tn, As, Bs, acc, wave, lane);

#pragma unroll
  for (int mi = 0; mi < 4; ++mi) {
#pragma unroll
    for (int ni = 0; ni < 4; ++ni) {
#pragma unroll
      for (int r = 0; r < 4; ++r) {
        int gm = tm + wr * 64 + mi * 16 + quad * 4 + r;
        int gn = tn + wc * 64 + ni * 16 + l15;
        float val = acc[mi][ni][r];
        if (z == 2) {  // Vt: [B][H][64][S]  f16
          int h = gm >> 6, dh = gm & 63, b = gn >> 11, s = gn & 2047;
          Vtw[(((size_t)(b * 16 + h) * 64 + dh) << 11) + s] = f2h(val);
        } else {       // Q/K: [B][H][S][64]  bf16
          int b = gm >> 11, s = gm & 2047, h = gn >> 6, dh = gn & 63;
          u16* dst = (z == 0) ? Qw : Kw;
          dst[(((size_t)(b * 16 + h) * 2048 + s) << 6) + dh] = f2bf(val);
        }
      }
    }
  }
}

// ---------- output projection: 64x128 tiles (512 blocks) ----------
__global__ __launch_bounds__(256, 3) void out_gemm(
    const u16* __restrict__ Ow, const u16* __restrict__ wob,
    float* __restrict__ C) {
  constexpr int K = 1024;
  __shared__ __align__(16) u16 As[64 * 64];
  __shared__ __align__(16) u16 Bs[128 * 64];
  const int tid = threadIdx.x, wave = tid >> 6, lane = tid & 63;
  const int l15 = lane & 15, quad = lane >> 4;
  const int wr = wave >> 1, wc = wave & 1;
  const int tm = blockIdx.y * 64, tn = blockIdx.x * 128;
  const int srow = lane >> 3;
  const int scol = ((lane & 7) ^ (srow & 7)) * 8;
  const u16* Ag = Ow + (size_t)(tm + wave * 16 + srow) * K + scol;
  const u16* Bg = wob + (size_t)(tn + wave * 32 + srow) * K + scol;
  const int rsw = l15 & 7;

  f32x4 acc[2][4] = {};
  for (int k0 = 0; k0 < K; k0 += 64) {
    __syncthreads();
#pragma unroll
    for (int c = 0; c < 2; ++c)
      GLOAD_LDS16(Ag + (size_t)c * 8 * K + k0, &As[(wave * 2 + c) * 512]);
#pragma unroll
    for (int c = 0; c < 4; ++c)
      GLOAD_LDS16(Bg + (size_t)c * 8 * K + k0, &Bs[(wave * 4 + c) * 512]);
    __syncthreads();
#pragma unroll
    for (int kq = 0; kq < 2; ++kq) {
      bf16x8 af[2], bfr[4];
#pragma unroll
      for (int mi = 0; mi < 2; ++mi)
        af[mi] = *(const bf16x8*)&As[(wr * 32 + mi * 16 + l15) * 64 +
                                     ((kq * 4 + quad) ^ rsw) * 8];
#pragma unroll
      for (int ni = 0; ni < 4; ++ni)
        bfr[ni] = *(const bf16x8*)&Bs[(wc * 64 + ni * 16 + l15) * 64 +
                                      ((kq * 4 + quad) ^ rsw) * 8];
#pragma unroll
      for (int mi = 0; mi < 2; ++mi)
#pragma unroll
        for (int ni = 0; ni < 4; ++ni)
          acc[mi][ni] = __builtin_amdgcn_mfma_f32_16x16x32_bf16(
              af[mi], bfr[ni], acc[mi][ni], 0, 0, 0);
    }
  }

#pragma unroll
  for (int mi = 0; mi < 2; ++mi)
#pragma unroll
    for (int ni = 0; ni < 4; ++ni)
#pragma unroll
      for (int r = 0; r < 4; ++r) {
        int gm = tm + wr * 32 + mi * 16 + quad * 4 + r;
        int gn = tn + wc * 64 + ni * 16 + l15;
        C[(size_t)gm * 1024 + gn] = acc[mi][ni][r];
      }
}

// ---------- attention v7: in-register P, no P LDS round-trip ----------
// Key identity: S^T C-layout (key=quad*4+r, q=l15) IS the A-operand layout of
// mfma_f32_16x16x16f16 (m=l15, k=quad*4+j). QK (bf16, S^T) -> exp2 -> cvt_pkrtz
// -> PV + den via 16x16x16 f16, V-frag = one swizzled ds_read_b64.
// 128 q/block, 4 waves x 32 q, kt=128, 2-barrier shared staging (R3 topology).
__global__ __launch_bounds__(256, 3) void attn_kernel(
    const u16* __restrict__ Qw, const u16* __restrict__ Kw,
    const u16* __restrict__ Vtw, const u16* __restrict__ maskb,
    u16* __restrict__ Ow) {
  constexpr int S = 2048;
  __shared__ __align__(16) u16 Ks[128 * 64];  // bf16 [key][dh]; blk c at slot c^(key&7)
  __shared__ __align__(16) u16 Vs[64 * 128];  // f16  [dh][key]; blk c at slot c^(dh&15)
  const int tid = threadIdx.x;
  const int wave = tid >> 6, lane = tid & 63;
  const int l15 = lane & 15, quad = lane >> 4;
  const int qt = blockIdx.x, h = blockIdx.y, b = blockIdx.z;
  const size_t head = ((size_t)(b * 16 + h)) * S * 64;
  const int qbase = qt * 128 + wave * 32;  // wave owns 32 q-rows

  // Q B-frags: B[n=q=l15][k=quad*8+j]; Qw pre-scaled by log2e/8
  bf16x8 qf[2][2];
#pragma unroll
  for (int q2 = 0; q2 < 2; ++q2)
#pragma unroll
    for (int kq = 0; kq < 2; ++kq)
      qf[q2][kq] = *(const bf16x8*)&Qw[head +
          (size_t)(qbase + q2 * 16 + l15) * 64 + kq * 32 + quad * 8];

  const _Float16 one_h = (_Float16)1.0f;
  const f16x4 ones = {one_h, one_h, one_h, one_h};

  f32x4 oa[2][4] = {};
  f32x4 den[2] = {};

  // K staging: chunk g = keys g*8..+7; lane: key=g*8+(l>>3), slot l&7 <- blk (l&7)^(key&7)
  const int k_r = lane >> 3;
  const int k_c = ((lane & 7) ^ k_r) * 8;
  // V staging: chunk g = dh g*4..+3; lane: dh=g*4+(l>>4), slot l&15 <- blk (l&15)^(dh&15)
  const int v_r = lane >> 4;
  const int v_cl = lane & 15;
  const int rsw = l15 & 7;

  for (int kt = 0; kt < S; kt += 128) {
    __syncthreads();
#pragma unroll
    for (int c = 0; c < 4; ++c) {
      int g = wave * 4 + c;
      GLOAD_LDS16(&Kw[head + (size_t)(kt + g * 8 + k_r) * 64 + k_c], &Ks[g * 512]);
    }
#pragma unroll
    for (int c = 0; c < 4; ++c) {
      int g = wave * 4 + c;
      int dh = g * 4 + v_r;
      GLOAD_LDS16(&Vtw[head + (size_t)dh * S + kt + ((v_cl ^ (dh & 15)) * 8)],
                  &Vs[g * 512]);
    }
    // mask prefetch (bf16, pre-scaled log2e): keys quad*4.. match S^T reg keys
    u16x4 mq[2][8];
#pragma unroll
    for (int q2 = 0; q2 < 2; ++q2)
#pragma unroll
      for (int mk = 0; mk < 8; ++mk)
        mq[q2][mk] = *(const u16x4*)&maskb[(size_t)(qbase + q2 * 16 + l15) * S +
                                           kt + mk * 16 + quad * 4];
    __syncthreads();

#pragma unroll
    for (int mk = 0; mk < 8; ++mk) {
      // S^T = K·Q^T for this 16-key tile
      f32x4 sa[2] = {};
#pragma unroll
      for (int kq = 0; kq < 2; ++kq) {
        bf16x8 ak = *(const bf16x8*)&Ks[(mk * 16 + l15) * 64 +
                                        ((kq * 4 + quad) ^ rsw) * 8];
        sa[0] = __builtin_amdgcn_mfma_f32_16x16x32_bf16(ak, qf[0][kq], sa[0], 0, 0, 0);
        sa[1] = __builtin_amdgcn_mfma_f32_16x16x32_bf16(ak, qf[1][kq], sa[1], 0, 0, 0);
      }
      // P = exp2(S + mask), packed f16 -> direct PV A-operand
      f16x4 pf[2];
#pragma unroll
      for (int q2 = 0; q2 < 2; ++q2) {
        float p0 = fexp2(sa[q2][0] + bf2f(mq[q2][mk].x));
        float p1 = fexp2(sa[q2][1] + bf2f(mq[q2][mk].y));
        float p2 = fexp2(sa[q2][2] + bf2f(mq[q2][mk].z));
        float p3 = fexp2(sa[q2][3] + bf2f(mq[q2][mk].w));
        union { struct { f16x2 lo, hi; } p; f16x4 v; } u;
        u.p.lo = pkf16(p0, p1); u.p.hi = pkf16(p2, p3);
        pf[q2] = u.v;
      }
      // V B-frags: B[k=key=quad*4+j][n=dh=l15]; one b64 per nv tile
#pragma unroll
      for (int nv = 0; nv < 4; ++nv) {
        f16x4 bv = *(const f16x4*)&Vs[(nv * 16 + l15) * 128 +
                                      ((mk * 2 + (quad >> 1)) ^ l15) * 8 +
                                      (quad & 1) * 4];
        oa[0][nv] = __builtin_amdgcn_mfma_f32_16x16x16f16(pf[0], bv, oa[0][nv], 0, 0, 0);
        oa[1][nv] = __builtin_amdgcn_mfma_f32_16x16x16f16(pf[1], bv, oa[1][nv], 0, 0, 0);
      }
      den[0] = __builtin_amdgcn_mfma_f32_16x16x16f16(pf[0], ones, den[0], 0, 0, 0);
      den[1] = __builtin_amdgcn_mfma_f32_16x16x16f16(pf[1], ones, den[1], 0, 0, 0);
    }
  }

  // epilogue: O / (den + 1e-10) -> Ow [B][S][H*64] bf16
#pragma unroll
  for (int q2 = 0; q2 < 2; ++q2) {
#pragma unroll
    for (int nv = 0; nv < 4; ++nv) {
#pragma unroll
      for (int r = 0; r < 4; ++r) {
        int srow = qbase + q2 * 16 + quad * 4 + r;
        int dh = nv * 16 + l15;
        float val = oa[q2][nv][r] / (den[q2][r] + 1e-10f);
        Ow[((size_t)(b * S + srow) << 10) + h * 64 + dh] = f2bf(val);
      }
    }
  }
}

extern "C" void kernel_launch(void* const* d_in, const int* in_sizes, int n_in,
                              void* d_out, int out_size, void* d_ws, size_t ws_size,
                              hipStream_t stream) {
  const float* x    = (const float*)d_in[0];
  const float* y    = (const float*)d_in[1];
  const float* mask = (const float*)d_in[2];
  const float* Wq   = (const float*)d_in[3];
  const float* Wk   = (const float*)d_in[4];
  const float* Wv   = (const float*)d_in[5];
  const float* Wo   = (const float*)d_in[6];
  char* ws = (char*)d_ws;
  const size_t MB = (size_t)1 << 20;
  u16* xb  = (u16*)(ws + 0  * MB);
  u16* yb  = (u16*)(ws + 8  * MB);
  u16* wqb = (u16*)(ws + 16 * MB);
  u16* wkb = (u16*)(ws + 18 * MB);
  u16* wvb = (u16*)(ws + 20 * MB);
  u16* wob = (u16*)(ws + 22 * MB);
  u16* Qw  = (u16*)(ws + 24 * MB);   // [B][H][S][64] bf16, scaled log2e/8
  u16* Kw  = (u16*)(ws + 32 * MB);   // [B][H][S][64] bf16
  u16* Vtw = (u16*)(ws + 40 * MB);   // [B][H][64][S] f16
  u16* Ow  = (u16*)(ws + 48 * MB);   // [B][S][1024] bf16
  u16* maskb = (u16*)(ws + 56 * MB); // [S][S] bf16, pre-scaled log2e

  convert_all<<<16384, 256, 0, stream>>>(x, y, Wq, Wk, Wv, Wo, mask,
                                         xb, yb, wqb, wkb, wvb, wob, maskb);
  qkv_gemm<<<dim3(8, 32, 3), 256, 0, stream>>>(xb, yb, wqb, wkb, wvb, Qw, Kw, Vtw);
  attn_kernel<<<dim3(16, 16, 2), 256, 0, stream>>>(Qw, Kw, Vtw, maskb, Ow);
  out_gemm<<<dim3(8, 64), 256, 0, stream>>>(Ow, wob, (float*)d_out);
  (void)in_sizes; (void)n_in; (void)out_size; (void)ws_size;
}